// Round 1
// baseline (368.286 us; speedup 1.0000x reference)
//
#include <hip/hip_runtime.h>
#include <math.h>

// Problem constants (from reference): B=32, L=2048, D_ENC=D_DEC=1024.
#define BB     32
#define LL     2048
#define DD     1024
#define SPLIT  64                     // L-chunks per batch (was 32)
#define WAVES  4
#define THREADS (WAVES * 64)
#define ROWS_PER_BLOCK (LL / SPLIT)   // 32
#define ROWS_PER_WAVE  (ROWS_PER_BLOCK / WAVES) // 8

// Workspace layout (floats):
//   part_c : [B][SPLIT][D]   = 32*64*1024 = 8 MiB
//   part_ms: [B][SPLIT][2]   (m, s)
#define PART_C_ELEMS ((size_t)BB * SPLIT * DD)

// ---------------------------------------------------------------------------
// Kernel 1: per-(batch, chunk) online-softmax partial.
// Softmax is shift-invariant, so the per-batch decoder term (dec·w_dec + b)
// cancels — we only need enc·w_enc. Each row of enc is read ONCE; the same
// registers feed the logit dot-product and the context accumulation.
// This revision processes TWO rows per iteration: the two 6-step __shfl_xor
// butterfly reductions interleave (2x ILP on the serial shuffle-latency
// chain) and the online rescale pays ONE alpha multiply for both rows.
// ---------------------------------------------------------------------------
__global__ __launch_bounds__(THREADS) void attn_partial(
    const float* __restrict__ enc, const float* __restrict__ W,
    float* __restrict__ part_c, float* __restrict__ part_ms)
{
    const int lane  = threadIdx.x & 63;
    const int wv    = threadIdx.x >> 6;
    const int chunk = blockIdx.x;
    const int bb    = blockIdx.y;

    // w_enc slice for this lane: d = j*256 + 4*lane + i, j = 0..3
    const float4* w4 = (const float4*)W; // W[0:1024] = w_enc
    const float4 w0 = w4[lane];
    const float4 w1 = w4[64  + lane];
    const float4 w2 = w4[128 + lane];
    const float4 w3 = w4[192 + lane];

    float m = -3.0e38f, s = 0.0f;
    float4 a0 = make_float4(0.f,0.f,0.f,0.f);
    float4 a1 = a0, a2 = a0, a3 = a0;

    const int row0 = chunk * ROWS_PER_BLOCK + wv * ROWS_PER_WAVE;
    const float4* base = (const float4*)enc + ((size_t)bb * LL + row0) * (DD / 4);

    for (int r = 0; r < ROWS_PER_WAVE; r += 2) {
        const float4* rpa = base + (size_t)r * (DD / 4);
        const float4* rpb = rpa + (DD / 4);
        // row a
        const float4 xa0 = rpa[lane];
        const float4 xa1 = rpa[64  + lane];
        const float4 xa2 = rpa[128 + lane];
        const float4 xa3 = rpa[192 + lane];
        // row b
        const float4 xb0 = rpb[lane];
        const float4 xb1 = rpb[64  + lane];
        const float4 xb2 = rpb[128 + lane];
        const float4 xb3 = rpb[192 + lane];

        float pa = xa0.x*w0.x + xa0.y*w0.y + xa0.z*w0.z + xa0.w*w0.w
                 + xa1.x*w1.x + xa1.y*w1.y + xa1.z*w1.z + xa1.w*w1.w
                 + xa2.x*w2.x + xa2.y*w2.y + xa2.z*w2.z + xa2.w*w2.w
                 + xa3.x*w3.x + xa3.y*w3.y + xa3.z*w3.z + xa3.w*w3.w;
        float pb = xb0.x*w0.x + xb0.y*w0.y + xb0.z*w0.z + xb0.w*w0.w
                 + xb1.x*w1.x + xb1.y*w1.y + xb1.z*w1.z + xb1.w*w1.w
                 + xb2.x*w2.x + xb2.y*w2.y + xb2.z*w2.z + xb2.w*w2.w
                 + xb3.x*w3.x + xb3.y*w3.y + xb3.z*w3.z + xb3.w*w3.w;

        // wave-wide reduce (64 lanes); the two chains are independent and
        // interleave, halving exposed ds-permute latency.
        #pragma unroll
        for (int off = 32; off > 0; off >>= 1) {
            pa += __shfl_xor(pa, off, 64);
            pb += __shfl_xor(pb, off, 64);
        }

        const float mn    = fmaxf(fmaxf(m, pa), pb);   // -> v_max3_f32
        const float alpha = __expf(m - mn);            // 0 on first iter
        const float ea    = __expf(pa - mn);
        const float eb    = __expf(pb - mn);
        s = s * alpha + ea + eb;
        a0.x = a0.x*alpha + ea*xa0.x + eb*xb0.x;  a0.y = a0.y*alpha + ea*xa0.y + eb*xb0.y;
        a0.z = a0.z*alpha + ea*xa0.z + eb*xb0.z;  a0.w = a0.w*alpha + ea*xa0.w + eb*xb0.w;
        a1.x = a1.x*alpha + ea*xa1.x + eb*xb1.x;  a1.y = a1.y*alpha + ea*xa1.y + eb*xb1.y;
        a1.z = a1.z*alpha + ea*xa1.z + eb*xb1.z;  a1.w = a1.w*alpha + ea*xa1.w + eb*xb1.w;
        a2.x = a2.x*alpha + ea*xa2.x + eb*xb2.x;  a2.y = a2.y*alpha + ea*xa2.y + eb*xb2.y;
        a2.z = a2.z*alpha + ea*xa2.z + eb*xb2.z;  a2.w = a2.w*alpha + ea*xa2.w + eb*xb2.w;
        a3.x = a3.x*alpha + ea*xa3.x + eb*xb3.x;  a3.y = a3.y*alpha + ea*xa3.y + eb*xb3.y;
        a3.z = a3.z*alpha + ea*xa3.z + eb*xb3.z;  a3.w = a3.w*alpha + ea*xa3.w + eb*xb3.w;
        m = mn;
    }

    // ---- combine the 4 waves of this block in LDS (parallel, 2 barriers) ----
    __shared__ float red_m[WAVES], red_s[WAVES];
    __shared__ float lacc[WAVES][DD];     // 16 KiB
    if (lane == 0) { red_m[wv] = m; red_s[wv] = s; }
    __syncthreads();

    const float M = fmaxf(fmaxf(red_m[0], red_m[1]), fmaxf(red_m[2], red_m[3]));
    float S = 0.0f;
    #pragma unroll
    for (int w = 0; w < WAVES; ++w) S += __expf(red_m[w] - M) * red_s[w];

    const float al = __expf(m - M);
    float4* l4 = (float4*)lacc[wv];
    float4 t;
    t.x = al*a0.x; t.y = al*a0.y; t.z = al*a0.z; t.w = al*a0.w; l4[lane]       = t;
    t.x = al*a1.x; t.y = al*a1.y; t.z = al*a1.z; t.w = al*a1.w; l4[64  + lane] = t;
    t.x = al*a2.x; t.y = al*a2.y; t.z = al*a2.z; t.w = al*a2.w; l4[128 + lane] = t;
    t.x = al*a3.x; t.y = al*a3.y; t.z = al*a3.z; t.w = al*a3.w; l4[192 + lane] = t;
    __syncthreads();

    // write block partial: each of the 256 threads owns one float4 of D
    const int pidx = bb * SPLIT + chunk;
    {
        const int i = threadIdx.x;                    // 0..255
        const float4* p0 = (const float4*)lacc[0];
        const float4* p1 = (const float4*)lacc[1];
        const float4* p2 = (const float4*)lacc[2];
        const float4* p3 = (const float4*)lacc[3];
        const float4 c0 = p0[i], c1 = p1[i], c2 = p2[i], c3 = p3[i];
        float4 c;
        c.x = c0.x + c1.x + c2.x + c3.x;
        c.y = c0.y + c1.y + c2.y + c3.y;
        c.z = c0.z + c1.z + c2.z + c3.z;
        c.w = c0.w + c1.w + c2.w + c3.w;
        ((float4*)part_c)[(size_t)pidx * (DD / 4) + i] = c;
    }
    if (threadIdx.x == 0) {
        part_ms[2 * pidx + 0] = M;
        part_ms[2 * pidx + 1] = S;
    }
}

// ---------------------------------------------------------------------------
// Kernel 2: combine SPLIT partials per batch, normalize, write context.
// Single streaming pass: acc = sum_p w_p * c_p, result = acc / S.
// No per-thread weight array (avoids SPLIT-sized register array).
// ---------------------------------------------------------------------------
__global__ __launch_bounds__(256) void attn_combine(
    const float* __restrict__ part_c, const float* __restrict__ part_ms,
    float* __restrict__ out)
{
    const int bb = blockIdx.x;
    const int t  = threadIdx.x;

    float M = -3.0e38f;
    #pragma unroll
    for (int p = 0; p < SPLIT; ++p)
        M = fmaxf(M, part_ms[2 * (bb * SPLIT + p) + 0]);

    float S = 0.0f;
    float4 acc = make_float4(0.f,0.f,0.f,0.f);
    #pragma unroll 4
    for (int p = 0; p < SPLIT; ++p) {
        const float mp = part_ms[2 * (bb * SPLIT + p) + 0];
        const float sp = part_ms[2 * (bb * SPLIT + p) + 1];
        const float w  = __expf(mp - M);
        S += w * sp;
        const float4 c = ((const float4*)part_c)[((size_t)(bb * SPLIT + p)) * (DD/4) + t];
        acc.x += w * c.x; acc.y += w * c.y;
        acc.z += w * c.z; acc.w += w * c.w;
    }
    const float inv = 1.0f / S;
    acc.x *= inv; acc.y *= inv; acc.z *= inv; acc.w *= inv;
    ((float4*)out)[bb * (DD/4) + t] = acc;
}

extern "C" void kernel_launch(void* const* d_in, const int* in_sizes, int n_in,
                              void* d_out, int out_size, void* d_ws, size_t ws_size,
                              hipStream_t stream) {
    const float* enc = (const float*)d_in[0];  // (32, 2048, 1024) fp32
    // d_in[1] = decoder_hidden — cancels under softmax (constant per batch)
    const float* W   = (const float*)d_in[2];  // (2048, 1) fp32; first 1024 = w_enc
    // d_in[3] = b — also cancels
    float* out = (float*)d_out;                // (32, 1, 1024) fp32

    float* part_c  = (float*)d_ws;
    float* part_ms = part_c + PART_C_ELEMS;

    dim3 grid1(SPLIT, BB);
    attn_partial<<<grid1, THREADS, 0, stream>>>(enc, W, part_c, part_ms);
    attn_combine<<<BB, 256, 0, stream>>>(part_c, part_ms, out);
}